// Round 6
// baseline (221.151 us; speedup 1.0000x reference)
//
#include <hip/hip_runtime.h>

static constexpr int B = 16, C = 64, H = 256, W = 256;
static constexpr int HW = H * W;              // 65536
static constexpr int KS = 7, PAD = 3;
static constexpr int TS = 16;                 // output tile
static constexpr int TI = TS + KS - 1;        // 22 = tile + halo
static constexpr int NPX = TI * TI;           // 484

typedef float f4 __attribute__((ext_vector_type(4)));
typedef unsigned short u16x4 __attribute__((ext_vector_type(4)));

__device__ __forceinline__ unsigned short f2bf(float f) {   // RNE fp32->bf16
    unsigned u = __float_as_uint(f);
    return (unsigned short)((u + 0x7FFFu + ((u >> 16) & 1u)) >> 16);
}

// One kernel, one pass over x.
// Block = 16x16 spatial tile x all 64 channels of one image.
// Phase A: stream the 22x22 halo region of x (1.89x issue, halo shared with
//          neighbor blocks via L2 thanks to XCD swizzle); per-pixel channel
//          sum/max accumulated in registers; center tile stashed bf16 in LDS.
// Phase B: 7x7 conv + sigmoid from LDS planes; multiply LDS tile; nt-store.
__global__ void __launch_bounds__(256, 4) fused_sam(
    const float* __restrict__ x, const float* __restrict__ wgt,
    const float* __restrict__ bias, float* __restrict__ out)
{
    __shared__ unsigned short sx[C][TS * TS];   // 32 KB bf16 center tile
    __shared__ float sa[NPX];                   // avg plane incl. halo
    __shared__ float sm[NPX];                   // max plane incl. halo
    __shared__ float smask[TS * TS];
    __shared__ float sw[2 * KS * KS];
    __shared__ float sbias;

    const int t = threadIdx.x;

    // XCD swizzle: blocks dispatch round-robin over 8 XCDs (bid & 7).
    // Give XCD k the contiguous work range [k*512, k*512+512) = 2 whole
    // images, so halo-sharing neighbor tiles run on the same XCD/L2.
    int bid  = blockIdx.x;
    int work = (bid & 7) * 512 + (bid >> 3);
    int b    = work >> 8;                       // image 0..15
    int tid  = work & 255;                      // tile 0..255 (16x16 grid)
    const int h0 = (tid >> 4) * TS, w0 = (tid & 15) * TS;

    if (t < 98) sw[t] = wgt[t];
    if (t == 98) sbias = bias[0];

    // two plane-pixels per thread: p0 = t (always), p1 = t+256 (t < 228)
    const int r0 = t / TI,  c0 = t - r0 * TI;
    const int p1 = t + 256;
    const int r1 = p1 / TI, c1 = p1 - r1 * TI;
    const bool have1 = (p1 < NPX);

    const int gh0 = h0 + r0 - PAD, gw0 = w0 + c0 - PAD;
    const int gh1 = h0 + r1 - PAD, gw1 = w0 + c1 - PAD;
    const bool ok0 = ((unsigned)gh0 < (unsigned)H) && ((unsigned)gw0 < (unsigned)W);
    const bool ok1 = have1 && ((unsigned)gh1 < (unsigned)H) && ((unsigned)gw1 < (unsigned)W);

    const float* xb  = x + (size_t)b * C * HW;
    const float* xp0 = xb + gh0 * W + gw0;      // stride HW per channel
    const float* xp1 = xb + gh1 * W + gw1;

    const bool ctr0 = ok0 && ((unsigned)(r0 - PAD) < TS) && ((unsigned)(c0 - PAD) < TS);
    const bool ctr1 = ok1 && ((unsigned)(r1 - PAD) < TS) && ((unsigned)(c1 - PAD) < TS);
    const int  ci0  = (r0 - PAD) * TS + (c0 - PAD);
    const int  ci1  = (r1 - PAD) * TS + (c1 - PAD);

    float s0 = 0.f, s1 = 0.f, m0 = -INFINITY, m1 = -INFINITY;
    #pragma unroll 4
    for (int c = 0; c < C; ++c) {
        float v0 = ok0 ? xp0[(size_t)c * HW] : 0.f;
        float v1 = ok1 ? xp1[(size_t)c * HW] : 0.f;
        s0 += v0; m0 = fmaxf(m0, v0);
        s1 += v1; m1 = fmaxf(m1, v1);
        if (ctr0) sx[c][ci0] = f2bf(v0);
        if (ctr1) sx[c][ci1] = f2bf(v1);
    }
    sa[t] = ok0 ? s0 * (1.0f / C) : 0.f;        // OOB plane pixels = 0 (zero pad)
    sm[t] = ok0 ? m0 : 0.f;
    if (have1) {
        sa[p1] = ok1 ? s1 * (1.0f / C) : 0.f;
        sm[p1] = ok1 ? m1 : 0.f;
    }
    __syncthreads();

    // conv + sigmoid: thread t = center pixel (r,cl)
    {
        const int r = t >> 4, cl = t & 15;
        float acc = sbias;
        #pragma unroll
        for (int ky = 0; ky < KS; ++ky) {
            const int rowb = (r + ky) * TI + cl;
            #pragma unroll
            for (int kx = 0; kx < KS; ++kx) {
                acc += sa[rowb + kx] * sw[ky * KS + kx];
                acc += sm[rowb + kx] * sw[49 + ky * KS + kx];
            }
        }
        smask[t] = 1.0f / (1.0f + expf(-acc));
    }
    __syncthreads();

    // multiply: wave wv owns channels [wv*16, wv*16+16); lane l covers
    // row = l>>2, col-group = l&3 (4 pixels = one f4).
    const int wv  = t >> 6;
    const int l   = t & 63;
    const int row = l >> 2, cg = l & 3;
    const int pix = row * TS + cg * 4;
    f4 mv = *reinterpret_cast<const f4*>(&smask[pix]);
    float* op = out + (size_t)b * C * HW + (size_t)(wv * 16) * HW
                    + (size_t)(h0 + row) * W + (w0 + cg * 4);
    #pragma unroll 4
    for (int k = 0; k < 16; ++k) {
        const int c = wv * 16 + k;
        u16x4 hv = *reinterpret_cast<const u16x4*>(&sx[c][pix]);
        f4 xv;
        xv.x = __uint_as_float((unsigned)hv.x << 16);
        xv.y = __uint_as_float((unsigned)hv.y << 16);
        xv.z = __uint_as_float((unsigned)hv.z << 16);
        xv.w = __uint_as_float((unsigned)hv.w << 16);
        __builtin_nontemporal_store(xv * mv, reinterpret_cast<f4*>(op));
        op += HW;
    }
}

extern "C" void kernel_launch(void* const* d_in, const int* in_sizes, int n_in,
                              void* d_out, int out_size, void* d_ws, size_t ws_size,
                              hipStream_t stream) {
    const float* x      = (const float*)d_in[0];
    const float* conv_w = (const float*)d_in[1];   // [1,2,7,7] OIHW flat
    const float* conv_b = (const float*)d_in[2];   // [1]
    float* out  = (float*)d_out;

    fused_sam<<<B * 256, 256, 0, stream>>>(x, conv_w, conv_b, out);
}

// Round 7
// 144.962 us; speedup vs baseline: 1.5256x; 1.5256x over previous
//
#include <hip/hip_runtime.h>

static constexpr int B = 16, C = 64, H = 256, W = 256;
static constexpr int HW = H * W;              // 65536
static constexpr int KS = 7, PAD = 3;

typedef float f4 __attribute__((ext_vector_type(4)));

// ---------------- Kernel 1: channel-wise mean & max (unchanged, r2) --------
// Thread = one pixel-quad (f4), loops over 64 channels (stride HW), fully
// coalesced 1 KiB/wave/instr.
__global__ void __launch_bounds__(256) reduce_mean_max(
    const float* __restrict__ x, float* __restrict__ avg, float* __restrict__ mx)
{
    int idx = blockIdx.x * 256 + threadIdx.x;     // over B*HW/4 = 262144
    int b   = idx >> 14;                          // HW/4 = 16384 = 2^14
    const f4* xp = reinterpret_cast<const f4*>(x)
                 + (size_t)b * (C * (HW / 4)) + (idx & (HW / 4 - 1));
    f4 v = xp[0];
    f4 s = v, a = v;
    #pragma unroll 8
    for (int c = 1; c < C; ++c) {
        f4 t = xp[(size_t)c * (HW / 4)];
        s += t;
        a.x = fmaxf(a.x, t.x); a.y = fmaxf(a.y, t.y);
        a.z = fmaxf(a.z, t.z); a.w = fmaxf(a.w, t.w);
    }
    const float inv = 1.0f / C;
    reinterpret_cast<f4*>(avg)[idx] = s * inv;
    reinterpret_cast<f4*>(mx)[idx]  = a;
}

// ---- Kernel 2 (fused conv+apply): block = 4 image rows x 256 cols --------
// Prologue: stage 10x262 avg/max halo from global (L2-hot, ~42 KB), compute
// 7x7 conv + sigmoid -> 4x256 mask in LDS (4 px/thread).
// Main: wave = one row (64 lanes x f4 = full 1 KB row), mask f4 held in a
// register, loop 64 channels: load x f4, nt-store out (never re-read).
__global__ void __launch_bounds__(256, 4) conv_apply(
    const float* __restrict__ x, const float* __restrict__ avg,
    const float* __restrict__ mx, const float* __restrict__ wgt,
    const float* __restrict__ bias, float* __restrict__ out)
{
    __shared__ float sa[10][264];     // rows h0-3..h0+6, cols -3..258 at +3
    __shared__ float sm[10][264];
    __shared__ float smask[4][256];
    __shared__ float sw[2 * KS * KS];
    __shared__ float sbias;

    const int t  = threadIdx.x;
    const int h0 = (int)blockIdx.x * 4;
    const int b  = (int)blockIdx.y;

    if (t < 98) sw[t] = wgt[t];
    if (t == 98) sbias = bias[0];

    const float* ap = avg + (size_t)b * HW;
    const float* mp = mx  + (size_t)b * HW;
    for (int e = t; e < 10 * 262; e += 256) {
        int r = e / 262, ci = e % 262;            // col = ci - 3
        int gh = h0 + r - PAD, gw = ci - PAD;
        bool ok = ((unsigned)gh < (unsigned)H) && ((unsigned)gw < (unsigned)W);
        int gi = gh * W + gw;
        sa[r][ci] = ok ? ap[gi] : 0.0f;
        sm[r][ci] = ok ? mp[gi] : 0.0f;
    }
    __syncthreads();

    // conv + sigmoid: thread t computes column t for rows 0..3
    #pragma unroll
    for (int r = 0; r < 4; ++r) {
        float acc = sbias;
        #pragma unroll
        for (int ky = 0; ky < KS; ++ky) {
            #pragma unroll
            for (int kx = 0; kx < KS; ++kx) {
                acc += sa[r + ky][t + kx] * sw[ky * KS + kx];
                acc += sm[r + ky][t + kx] * sw[49 + ky * KS + kx];
            }
        }
        smask[r][t] = 1.0f / (1.0f + expf(-acc));
    }
    __syncthreads();

    // multiply: wave = one row, 1 KB contiguous per instruction
    const int row = t >> 6;          // 0..3
    const int q   = t & 63;          // f4 index within the row
    f4 mv = reinterpret_cast<const f4*>(&smask[row][0])[q];
    size_t base = (((size_t)b * C) * H + (h0 + row)) * (W / 4) + q;   // f4 units
    const f4* xp = reinterpret_cast<const f4*>(x)   + base;
    f4*       op = reinterpret_cast<f4*>(out)       + base;
    #pragma unroll 8
    for (int c = 0; c < C; ++c) {
        f4 xv = xp[(size_t)c * (HW / 4)];
        __builtin_nontemporal_store(xv * mv, op + (size_t)c * (HW / 4));
    }
}

extern "C" void kernel_launch(void* const* d_in, const int* in_sizes, int n_in,
                              void* d_out, int out_size, void* d_ws, size_t ws_size,
                              hipStream_t stream) {
    const float* x      = (const float*)d_in[0];
    const float* conv_w = (const float*)d_in[1];   // [1,2,7,7] OIHW flat
    const float* conv_b = (const float*)d_in[2];   // [1]
    float* out  = (float*)d_out;

    float* avg  = (float*)d_ws;                    // B*HW floats = 4 MiB
    float* mx   = avg + (size_t)B * HW;            // 4 MiB

    reduce_mean_max<<<(B * HW / 4) / 256, 256, 0, stream>>>(x, avg, mx);

    dim3 g(H / 4, B);
    conv_apply<<<g, 256, 0, stream>>>(x, avg, mx, conv_w, conv_b, out);
}